// Round 9
// baseline (199.224 us; speedup 1.0000x reference)
//
#include <hip/hip_runtime.h>
#include <hip/hip_bf16.h>
#include <math.h>

// Problem constants (match reference)
#define BB 2
#define LL 4096
#define DD 128
#define ED 256
#define NN 16
#define KK 4
#define RR 8
#define HH 256
#define NT (BB*LL)          // 8192 tokens
#define NC 128              // chunks for scan
#define LC 32               // chunk length (NC*LC == LL)

typedef __attribute__((ext_vector_type(8))) short short8;
typedef __attribute__((ext_vector_type(8))) unsigned short ushort8v;
typedef __attribute__((ext_vector_type(4))) float floatx4;

__device__ __forceinline__ unsigned short f2bf(float f) {
  unsigned int b = __builtin_bit_cast(unsigned int, f);
  b += 0x7FFFu + ((b >> 16) & 1u);           // round-to-nearest-even
  return (unsigned short)(b >> 16);
}

__device__ __forceinline__ ushort8v pack8(const float4& v0, const float4& v1) {
  ushort8v p;
  p[0]=f2bf(v0.x); p[1]=f2bf(v0.y); p[2]=f2bf(v0.z); p[3]=f2bf(v0.w);
  p[4]=f2bf(v1.x); p[5]=f2bf(v1.y); p[6]=f2bf(v1.z); p[7]=f2bf(v1.w);
  return p;
}

// ---------------------------------------------------------------------------
// in_proj GEMM with fused double-LayerNorm on A and inline fp32->bf16 weight
// conversion. xz[M,512] = LN2(LN1(x)) @ in_w^T.  K = 128 = LN width.
// ---------------------------------------------------------------------------
__global__ __launch_bounds__(256) void gemm_inln_k(const float* __restrict__ x,
    const float* __restrict__ g1, const float* __restrict__ b1,
    const float* __restrict__ g2, const float* __restrict__ b2,
    const float* __restrict__ W, float* __restrict__ C) {
  __shared__ unsigned short As[64][136];
  __shared__ unsigned short Ws[64][136];
  const int row0 = blockIdx.y * 64;
  const int col0 = blockIdx.x * 64;
  const int tid  = threadIdx.x;
  const int wave = tid >> 6, lane = tid & 63;
  const int quad = lane >> 4, l16 = lane & 15;
  const int wm = (wave & 1) * 32, wn = (wave >> 1) * 32;
  const int lr = tid >> 2;            // staging row 0..63
  const int lk = (tid & 3) * 32;      // staging col (32 floats)

  // --- A staging with double LN ---
  {
    const float* Ap = x + (size_t)(row0 + lr)*DD + lk;
    float4 av[8];
    float s = 0.f, sq = 0.f;
    #pragma unroll
    for (int g = 0; g < 8; g++) {
      av[g] = *(const float4*)(Ap + g*4);
      s  += av[g].x + av[g].y + av[g].z + av[g].w;
      sq += av[g].x*av[g].x + av[g].y*av[g].y + av[g].z*av[g].z + av[g].w*av[g].w;
    }
    s += __shfl_xor(s, 1);  s += __shfl_xor(s, 2);
    sq += __shfl_xor(sq, 1); sq += __shfl_xor(sq, 2);
    const float m1 = s * (1.f/128.f);
    const float rs1 = rsqrtf(sq*(1.f/128.f) - m1*m1 + 1e-5f);
    float s2 = 0.f, sq2 = 0.f;
    #pragma unroll
    for (int g = 0; g < 8; g++) {
      const float4 gg = *(const float4*)(g1 + lk + g*4);
      const float4 bb = *(const float4*)(b1 + lk + g*4);
      av[g].x = (av[g].x - m1)*rs1*gg.x + bb.x;
      av[g].y = (av[g].y - m1)*rs1*gg.y + bb.y;
      av[g].z = (av[g].z - m1)*rs1*gg.z + bb.z;
      av[g].w = (av[g].w - m1)*rs1*gg.w + bb.w;
      s2  += av[g].x + av[g].y + av[g].z + av[g].w;
      sq2 += av[g].x*av[g].x + av[g].y*av[g].y + av[g].z*av[g].z + av[g].w*av[g].w;
    }
    s2 += __shfl_xor(s2, 1);  s2 += __shfl_xor(s2, 2);
    sq2 += __shfl_xor(sq2, 1); sq2 += __shfl_xor(sq2, 2);
    const float m2 = s2 * (1.f/128.f);
    const float rs2 = rsqrtf(sq2*(1.f/128.f) - m2*m2 + 1e-5f);
    #pragma unroll
    for (int g = 0; g < 4; g++) {
      const float4 ga = *(const float4*)(g2 + lk + g*8);
      const float4 gb = *(const float4*)(g2 + lk + g*8 + 4);
      const float4 ba = *(const float4*)(b2 + lk + g*8);
      const float4 bbv= *(const float4*)(b2 + lk + g*8 + 4);
      ushort8v pa;
      pa[0] = f2bf((av[2*g].x   - m2)*rs2*ga.x + ba.x);
      pa[1] = f2bf((av[2*g].y   - m2)*rs2*ga.y + ba.y);
      pa[2] = f2bf((av[2*g].z   - m2)*rs2*ga.z + ba.z);
      pa[3] = f2bf((av[2*g].w   - m2)*rs2*ga.w + ba.w);
      pa[4] = f2bf((av[2*g+1].x - m2)*rs2*gb.x + bbv.x);
      pa[5] = f2bf((av[2*g+1].y - m2)*rs2*gb.y + bbv.y);
      pa[6] = f2bf((av[2*g+1].z - m2)*rs2*gb.z + bbv.z);
      pa[7] = f2bf((av[2*g+1].w - m2)*rs2*gb.w + bbv.w);
      *(ushort8v*)&As[lr][lk + g*8] = pa;
    }
  }
  // --- W staging with inline conversion ---
  {
    const float* Wp = W + (size_t)(col0 + lr)*DD + lk;
    #pragma unroll
    for (int g = 0; g < 4; g++) {
      const float4 v0 = *(const float4*)(Wp + g*8);
      const float4 v1 = *(const float4*)(Wp + g*8 + 4);
      *(ushort8v*)&Ws[lr][lk + g*8] = pack8(v0, v1);
    }
  }
  __syncthreads();

  floatx4 acc[2][2] = {};
  #pragma unroll
  for (int ks = 0; ks < 4; ks++) {
    const int ko = ks*32 + quad*8;
    short8 a0 = *(const short8*)&As[wm +      l16][ko];
    short8 a1 = *(const short8*)&As[wm + 16 + l16][ko];
    short8 b0 = *(const short8*)&Ws[wn +      l16][ko];
    short8 b1 = *(const short8*)&Ws[wn + 16 + l16][ko];
    acc[0][0] = __builtin_amdgcn_mfma_f32_16x16x32_bf16(a0, b0, acc[0][0], 0, 0, 0);
    acc[0][1] = __builtin_amdgcn_mfma_f32_16x16x32_bf16(a0, b1, acc[0][1], 0, 0, 0);
    acc[1][0] = __builtin_amdgcn_mfma_f32_16x16x32_bf16(a1, b0, acc[1][0], 0, 0, 0);
    acc[1][1] = __builtin_amdgcn_mfma_f32_16x16x32_bf16(a1, b1, acc[1][1], 0, 0, 0);
  }
  #pragma unroll
  for (int i = 0; i < 2; i++)
    #pragma unroll
    for (int j = 0; j < 2; j++) {
      const int n = col0 + wn + j*16 + l16;
      #pragma unroll
      for (int r = 0; r < 4; r++) {
        const int m = row0 + wm + i*16 + quad*4 + r;
        C[(size_t)m*(2*ED) + n] = acc[i][j][r];
      }
    }
}

// ---------------------------------------------------------------------------
// Fused scan phase 1: conv+silu -> xproj(MFMA, inline W convert) -> delta ->
// per-chunk scan summaries. Grid (eb, c, b), 512 blocks, 2/CU.
// ---------------------------------------------------------------------------
__global__ __launch_bounds__(256) void scan1f_k(
    const float* __restrict__ xz, const float* __restrict__ cw,
    const float* __restrict__ cb, const float* __restrict__ xpw,
    const float* __restrict__ dtw, const float* __restrict__ dtb,
    const float* __restrict__ A_log, float* __restrict__ uc,
    float* __restrict__ dbc, float* __restrict__ delta,
    float* __restrict__ cA, float* __restrict__ cH) {
  __shared__ __align__(16) unsigned short Bs[64][264];
  __shared__ __align__(16) unsigned short As[32][264];
  __shared__ float su[32][128];
  __shared__ float sdbc[32][40];
  float (*sdel)[128] = reinterpret_cast<float(*)[128]>(&As[0][0]); // aliases As

  const int eb = blockIdx.x, c = blockIdx.y, b = blockIdx.z;
  const int tid = threadIdx.x;
  const int t0 = b*LL + c*LC;

  // stage xproj weights with inline conversion (rows >= 40 zeroed)
  #pragma unroll
  for (int p = 0; p < 8; p++) {
    const int idx = p*256 + tid;           // 2048 chunks of 8 shorts
    const int row = idx >> 5;
    const int col = (idx & 31) * 8;
    ushort8v v = {};
    if (row < 40) {
      const float4 v0 = *(const float4*)(xpw + (size_t)row*ED + col);
      const float4 v1 = *(const float4*)(xpw + (size_t)row*ED + col + 4);
      v = pack8(v0, v1);
    }
    *(ushort8v*)&Bs[row][col] = v;
  }

  // conv: rolling window, all 256 channels
  {
    const int ch = tid;
    const float4 w = *(const float4*)(cw + ch*4);
    const float cbe = cb[ch];
    float h0 = 0.f, h1 = 0.f, h2 = 0.f;
    if (c != 0) {
      h0 = xz[(size_t)(t0-3)*(2*ED) + ch];
      h1 = xz[(size_t)(t0-2)*(2*ED) + ch];
      h2 = xz[(size_t)(t0-1)*(2*ED) + ch];
    }
    const bool own = (ch >> 7) == eb;
    #pragma unroll 8
    for (int i = 0; i < LC; i++) {
      const float cur = xz[(size_t)(t0+i)*(2*ED) + ch];
      const float a = cbe + h0*w.x + h1*w.y + h2*w.z + cur*w.w;
      const float s = a / (1.f + __expf(-a));
      As[i][ch] = f2bf(s);
      if (own) {
        su[i][ch & 127] = s;
        uc[(size_t)(t0+i)*ED + ch] = s;
      }
      h0 = h1; h1 = h2; h2 = cur;
    }
  }
  __syncthreads();

  // xproj MFMA: M=32, N=64(pad), K=256
  const int wave = tid >> 6, lane = tid & 63;
  const int quad = lane >> 4, l16 = lane & 15;
  {
    const int mi = (wave & 1) * 16;
    const int j0 = (wave >> 1) * 2;
    floatx4 acc[2] = {};
    #pragma unroll
    for (int ks = 0; ks < 8; ks++) {
      const int ko = ks*32 + quad*8;
      short8 a  = *(const short8*)&As[mi + l16][ko];
      short8 b0 = *(const short8*)&Bs[j0*16 +      l16][ko];
      short8 b1 = *(const short8*)&Bs[j0*16 + 16 + l16][ko];
      acc[0] = __builtin_amdgcn_mfma_f32_16x16x32_bf16(a, b0, acc[0], 0, 0, 0);
      acc[1] = __builtin_amdgcn_mfma_f32_16x16x32_bf16(a, b1, acc[1], 0, 0, 0);
    }
    __syncthreads();   // As reads done before sdel aliases As
    #pragma unroll
    for (int f = 0; f < 2; f++) {
      const int n = (j0 + f)*16 + l16;
      #pragma unroll
      for (int r = 0; r < 4; r++) {
        const int m = mi + quad*4 + r;
        if (n < 40) {
          sdbc[m][n] = acc[f][r];
          if (eb == 0) dbc[(size_t)(t0 + m)*40 + n] = acc[f][r];
        }
      }
    }
  }
  __syncthreads();

  // delta: softplus(dt @ dt_w^T + dt_b) for own 128 channels
  const int e_loc = tid >> 1;
  const int half  = tid & 1;
  const int e     = eb*128 + e_loc;
  {
    const float4 w0 = *(const float4*)(dtw + e*RR);
    const float4 w1 = *(const float4*)(dtw + e*RR + 4);
    const float db = dtb[e];
    #pragma unroll 4
    for (int i = 0; i < 16; i++) {
      const int t = half*16 + i;
      const float a = db
          + sdbc[t][0]*w0.x + sdbc[t][1]*w0.y + sdbc[t][2]*w0.z + sdbc[t][3]*w0.w
          + sdbc[t][4]*w1.x + sdbc[t][5]*w1.y + sdbc[t][6]*w1.z + sdbc[t][7]*w1.w;
      const float d = (a > 20.f) ? a : log1pf(__expf(a));
      sdel[t][e_loc] = d;
      delta[(size_t)(t0+t)*ED + e] = d;
    }
  }
  __syncthreads();

  // per-chunk scan summaries; thread owns (e, n-half)
  const int n0 = half * 8;
  const float4 a0 = *(const float4*)(A_log + e*NN + n0);
  const float4 a1 = *(const float4*)(A_log + e*NN + n0 + 4);
  float Aen[8] = {-__expf(a0.x), -__expf(a0.y), -__expf(a0.z), -__expf(a0.w),
                  -__expf(a1.x), -__expf(a1.y), -__expf(a1.z), -__expf(a1.w)};
  float h[8] = {};
  float sumd = 0.f;
  for (int i = 0; i < LC; i++) {
    const float dv = sdel[i][e_loc];
    const float du = dv * su[i][e_loc];
    const float4 B0 = *(const float4*)&sdbc[i][RR + n0];
    const float4 B1 = *(const float4*)&sdbc[i][RR + n0 + 4];
    const float Bv[8] = {B0.x,B0.y,B0.z,B0.w,B1.x,B1.y,B1.z,B1.w};
    sumd += dv;
    #pragma unroll
    for (int j = 0; j < 8; j++)
      h[j] = __expf(dv * Aen[j])*h[j] + Bv[j]*du;
  }
  const size_t base = (((size_t)c*BB + b)*ED + e)*NN + n0;
  *(float4*)(cA + base)     = make_float4(__expf(sumd*Aen[0]), __expf(sumd*Aen[1]),
                                          __expf(sumd*Aen[2]), __expf(sumd*Aen[3]));
  *(float4*)(cA + base + 4) = make_float4(__expf(sumd*Aen[4]), __expf(sumd*Aen[5]),
                                          __expf(sumd*Aen[6]), __expf(sumd*Aen[7]));
  *(float4*)(cH + base)     = make_float4(h[0], h[1], h[2], h[3]);
  *(float4*)(cH + base + 4) = make_float4(h[4], h[5], h[6], h[7]);
}

// ---------------------------------------------------------------------------
// Scan phase 2: scan over NC chunk summaries, in-place prefix into cA.
// ---------------------------------------------------------------------------
__global__ __launch_bounds__(256) void scan2_k(float* __restrict__ cA,
    const float* __restrict__ cH) {
  const int gt = blockIdx.x*256 + threadIdx.x;   // [0, BB*ED*NN)
  const int b = gt >> 12;
  const size_t base = (size_t)b*ED*NN + (gt & 4095);
  float h = 0.f;
  for (int g = 0; g < NC/16; g++) {
    float av[16], hv[16];
    #pragma unroll
    for (int i = 0; i < 16; i++) {
      const size_t idx = (size_t)(g*16 + i)*(BB*ED*NN) + base;
      av[i] = cA[idx]; hv[i] = cH[idx];
    }
    #pragma unroll
    for (int i = 0; i < 16; i++) {
      const size_t idx = (size_t)(g*16 + i)*(BB*ED*NN) + base;
      cA[idx] = h;
      h = av[i]*h + hv[i];
    }
  }
}

// ---------------------------------------------------------------------------
// Mega-tail v2: 16-token blocks -> 512 blocks = 2/CU (vs round 8's 1/CU).
// Odd sub-chunk blocks replay 16 warm-up tokens (h-only) from the 32-token
// prefix -- identical fp32 op order, so y is bit-identical to round 8.
// Weights streamed bf16 in 128-wide halves (BigW 34.8 KB); LDS ~55.8 KB.
// Phases: scan replay + gate -> y(LDS) -> out_proj + residual -> norm1 ->
// fc1 + gelu -> fc2 + bias + residual -> out.
// ---------------------------------------------------------------------------
__global__ __launch_bounds__(256, 2) void tail2_k(
    const float* __restrict__ xz, const float* __restrict__ delta,
    const float* __restrict__ uc, const float* __restrict__ dbc,
    const float* __restrict__ cP, const float* __restrict__ A_log,
    const float* __restrict__ Dpv, const float* __restrict__ x,
    const float* __restrict__ g1, const float* __restrict__ b1,
    const float* __restrict__ out_w, const float* __restrict__ fc1_w,
    const float* __restrict__ fc1_b, const float* __restrict__ fc2_w,
    const float* __restrict__ fc2_b, float* __restrict__ out) {
  __shared__ __align__(16) unsigned short BigW[128*136];  // 34.8 KB
  __shared__ __align__(16) unsigned short Au[16][264];    // y -> hln -> h
  __shared__ float xs[16][132];                           // xnew tile fp32
  __shared__ float sbc[32][32];                           // B|C, whole 32-chunk

  const int c2 = blockIdx.x, b = blockIdx.y;
  const int c = c2 >> 1, odd = c2 & 1;
  const int tc0 = b*LL + c*LC;        // 32-chunk token base
  const int t0  = b*LL + c2*16;       // own 16-token base
  const int tid = threadIdx.x;
  const int wave = tid >> 6, lane = tid & 63;
  const int quad = lane >> 4, l16 = lane & 15;
  const int wn = wave * 32;

  // --- stage B/C for the whole 32-token chunk ---
  #pragma unroll
  for (int p = 0; p < 4; p++) {
    const int idx = p*256 + tid;
    const int row = idx >> 5, col = idx & 31;
    sbc[row][col] = dbc[(size_t)(tc0 + row)*40 + RR + col];
  }

  // --- scan replay: thread = e, h[16] in regs ---
  {
    const int e = tid;
    float Aen[16], h[16];
    #pragma unroll
    for (int g = 0; g < 4; g++) {
      const float4 a = *(const float4*)(A_log + e*NN + g*4);
      Aen[4*g]=-__expf(a.x); Aen[4*g+1]=-__expf(a.y);
      Aen[4*g+2]=-__expf(a.z); Aen[4*g+3]=-__expf(a.w);
      const float4 hp = *(const float4*)(cP + (((size_t)c*BB + b)*ED + e)*NN + g*4);
      h[4*g]=hp.x; h[4*g+1]=hp.y; h[4*g+2]=hp.z; h[4*g+3]=hp.w;
    }
    const float Dpe = Dpv[e];
    __syncthreads();     // sbc ready
    if (odd) {           // warm-up: advance carry over tokens 0..15 (h only)
      #pragma unroll 4
      for (int i = 0; i < 16; i++) {
        const float dv = delta[(size_t)(tc0+i)*ED + e];
        const float du = dv * uc[(size_t)(tc0+i)*ED + e];
        #pragma unroll
        for (int j = 0; j < 16; j++)
          h[j] = __expf(dv * Aen[j])*h[j] + sbc[i][j]*du;
      }
    }
    const int ib = odd * 16;
    #pragma unroll 4
    for (int i = 0; i < 16; i++) {
      const float dv = delta[(size_t)(t0+i)*ED + e];
      const float uv = uc[(size_t)(t0+i)*ED + e];
      const float du = dv * uv;
      float part = 0.f;
      #pragma unroll
      for (int j = 0; j < 16; j++) {
        h[j] = __expf(dv * Aen[j])*h[j] + sbc[ib+i][j]*du;
        part += h[j]*sbc[ib+i][16+j];
      }
      const float zv = xz[(size_t)(t0+i)*(2*ED) + ED + e];
      const float g = zv / (1.f + __expf(-zv));
      Au[i][e] = f2bf((part + uv*Dpe) * g);
    }
  }

  // --- out_proj MFMA: M=16, N=128, K=256 streamed in 2 chunks ---
  {
    floatx4 acc[2] = {};
    for (int ks0 = 0; ks0 < ED; ks0 += 128) {
      __syncthreads();   // prev BigW reads done; Au writes visible (1st iter)
      const int r = tid >> 1, k0 = (tid & 1) * 64;
      const float* wp = out_w + (size_t)r*ED + ks0 + k0;
      #pragma unroll
      for (int g = 0; g < 8; g++) {
        const float4 v0 = *(const float4*)(wp + g*8);
        const float4 v1 = *(const float4*)(wp + g*8 + 4);
        *(ushort8v*)&BigW[r*136 + k0 + g*8] = pack8(v0, v1);
      }
      __syncthreads();
      #pragma unroll
      for (int ks = 0; ks < 4; ks++) {
        const int ko = ks*32 + quad*8;
        short8 a  = *(const short8*)&Au[l16][ks0 + ko];
        short8 b0 = *(const short8*)&BigW[(wn +      l16)*136 + ko];
        short8 b1 = *(const short8*)&BigW[(wn + 16 + l16)*136 + ko];
        acc[0] = __builtin_amdgcn_mfma_f32_16x16x32_bf16(a, b0, acc[0], 0, 0, 0);
        acc[1] = __builtin_amdgcn_mfma_f32_16x16x32_bf16(a, b1, acc[1], 0, 0, 0);
      }
    }
    #pragma unroll
    for (int j = 0; j < 2; j++) {
      const int n = wn + j*16 + l16;
      #pragma unroll
      for (int r = 0; r < 4; r++) {
        const int m = quad*4 + r;
        xs[m][n] = acc[j][r] + x[(size_t)(t0 + m)*DD + n];
      }
    }
  }
  __syncthreads();

  // --- norm1 per row (16 threads/row, 8 elems each) -> hln into Au[.,0:128]
  {
    const int lr = tid >> 4, le = (tid & 15) * 8;
    float vv[8];
    float s = 0.f, sq = 0.f;
    #pragma unroll
    for (int i = 0; i < 8; i++) {
      vv[i] = xs[lr][le + i];
      s += vv[i]; sq += vv[i]*vv[i];
    }
    s += __shfl_xor(s, 1);  s += __shfl_xor(s, 2);
    s += __shfl_xor(s, 4);  s += __shfl_xor(s, 8);
    sq += __shfl_xor(sq, 1); sq += __shfl_xor(sq, 2);
    sq += __shfl_xor(sq, 4); sq += __shfl_xor(sq, 8);
    const float mean = s * (1.f/128.f);
    const float rs = rsqrtf(sq*(1.f/128.f) - mean*mean + 1e-5f);
    ushort8v p;
    #pragma unroll
    for (int i = 0; i < 8; i++)
      p[i] = f2bf((vv[i] - mean)*rs*g1[le + i] + b1[le + i]);
    *(ushort8v*)&Au[lr][le] = p;
  }

  // --- fc1 MFMA: M=16, K=128, N=256 in 2 row-halves (high half first) ---
  for (int hh = 1; hh >= 0; hh--) {
    __syncthreads();   // BigW reuse; norm writes visible (1st iter)
    const int rr = tid >> 1, k0 = (tid & 1) * 64;
    const float* wp = fc1_w + (size_t)(hh*128 + rr)*DD + k0;
    #pragma unroll
    for (int g = 0; g < 8; g++) {
      const float4 v0 = *(const float4*)(wp + g*8);
      const float4 v1 = *(const float4*)(wp + g*8 + 4);
      *(ushort8v*)&BigW[rr*136 + k0 + g*8] = pack8(v0, v1);
    }
    __syncthreads();
    floatx4 acc[2] = {};
    #pragma unroll
    for (int ks = 0; ks < 4; ks++) {
      const int ko = ks*32 + quad*8;
      short8 a  = *(const short8*)&Au[l16][ko];
      short8 b0 = *(const short8*)&BigW[(wn +      l16)*136 + ko];
      short8 b1 = *(const short8*)&BigW[(wn + 16 + l16)*136 + ko];
      acc[0] = __builtin_amdgcn_mfma_f32_16x16x32_bf16(a, b0, acc[0], 0, 0, 0);
      acc[1] = __builtin_amdgcn_mfma_f32_16x16x32_bf16(a, b1, acc[1], 0, 0, 0);
    }
    if (hh == 0) __syncthreads();   // all hln reads done before overwrite
    #pragma unroll
    for (int j = 0; j < 2; j++) {
      const int n = wn + j*16 + l16;
      const float bn = fc1_b[hh*128 + n];
      #pragma unroll
      for (int r = 0; r < 4; r++) {
        const int m = quad*4 + r;
        float v = acc[j][r] + bn;
        v = 0.5f*v*(1.f + erff(v*0.70710678118f));
        Au[m][hh*128 + n] = f2bf(v);
      }
    }
  }

  // --- fc2 MFMA: M=16, N=128, K=256 streamed in 2 chunks; +bias +residual ---
  {
    floatx4 acc[2] = {};
    for (int ks0 = 0; ks0 < HH; ks0 += 128) {
      __syncthreads();   // BigW reuse; fc1 writes visible
      const int r = tid >> 1, k0 = (tid & 1) * 64;
      const float* wp = fc2_w + (size_t)r*HH + ks0 + k0;
      #pragma unroll
      for (int g = 0; g < 8; g++) {
        const float4 v0 = *(const float4*)(wp + g*8);
        const float4 v1 = *(const float4*)(wp + g*8 + 4);
        *(ushort8v*)&BigW[r*136 + k0 + g*8] = pack8(v0, v1);
      }
      __syncthreads();
      #pragma unroll
      for (int ks = 0; ks < 4; ks++) {
        const int ko = ks*32 + quad*8;
        short8 a  = *(const short8*)&Au[l16][ks0 + ko];
        short8 b0 = *(const short8*)&BigW[(wn +      l16)*136 + ko];
        short8 b1 = *(const short8*)&BigW[(wn + 16 + l16)*136 + ko];
        acc[0] = __builtin_amdgcn_mfma_f32_16x16x32_bf16(a, b0, acc[0], 0, 0, 0);
        acc[1] = __builtin_amdgcn_mfma_f32_16x16x32_bf16(a, b1, acc[1], 0, 0, 0);
      }
    }
    #pragma unroll
    for (int j = 0; j < 2; j++) {
      const int n = wn + j*16 + l16;
      const float bn = fc2_b[n];
      #pragma unroll
      for (int r = 0; r < 4; r++) {
        const int m = quad*4 + r;
        out[(size_t)(t0 + m)*DD + n] = acc[j][r] + bn + xs[m][n];
      }
    }
  }
}

// ---------------------------------------------------------------------------
extern "C" void kernel_launch(void* const* d_in, const int* in_sizes, int n_in,
                              void* d_out, int out_size, void* d_ws, size_t ws_size,
                              hipStream_t stream) {
  const float* x      = (const float*)d_in[0];
  const float* n1g    = (const float*)d_in[1];
  const float* n1b    = (const float*)d_in[2];
  const float* ing    = (const float*)d_in[3];
  const float* inb    = (const float*)d_in[4];
  const float* in_w   = (const float*)d_in[5];
  const float* conv_w = (const float*)d_in[6];
  const float* conv_b = (const float*)d_in[7];
  const float* xproj_w= (const float*)d_in[8];
  const float* dt_w   = (const float*)d_in[9];
  const float* dt_b   = (const float*)d_in[10];
  const float* A_log  = (const float*)d_in[11];
  const float* Dpv    = (const float*)d_in[12];
  const float* out_w  = (const float*)d_in[13];
  const float* fc1_w  = (const float*)d_in[14];
  const float* fc1_b  = (const float*)d_in[15];
  const float* fc2_w  = (const float*)d_in[16];
  const float* fc2_b  = (const float*)d_in[17];
  float* out = (float*)d_out;

  // Workspace layout (~37 MB)
  float* ws    = (float*)d_ws;
  float* xz    = ws;                          // [NT,512]
  float* uc    = xz    + (size_t)NT*2*ED;     // [NT,256]
  float* dbc   = uc    + (size_t)NT*ED;       // [NT,40]
  float* delta = dbc   + (size_t)NT*40;       // [NT,256]
  float* cAP   = delta + (size_t)NT*ED;       // [NC,B,ED,N]
  float* cH    = cAP   + (size_t)NC*BB*ED*NN;

  // 1) xz = LN2(LN1(x)) @ in_w^T   (LN + weight-convert fused)
  gemm_inln_k<<<dim3(512/64, NT/64), 256, 0, stream>>>(x, n1g, n1b, ing, inb, in_w, xz);
  // 2) conv+silu -> xproj(MFMA) -> delta -> chunk summaries
  scan1f_k<<<dim3(2, NC, BB), 256, 0, stream>>>(xz, conv_w, conv_b, xproj_w, dt_w, dt_b,
                                                A_log, uc, dbc, delta, cAP, cH);
  // 3) inter-chunk prefix
  scan2_k<<<(BB*ED*NN)/256, 256, 0, stream>>>(cAP, cH);
  // 4) scan replay + gate + out_proj + LN + MLP + residuals -> out (2 blocks/CU)
  tail2_k<<<dim3(2*NC, BB), 256, 0, stream>>>(xz, delta, uc, dbc, cAP, A_log, Dpv,
                                              x, n1g, n1b, out_w, fc1_w, fc1_b,
                                              fc2_w, fc2_b, out);
}

// Round 10
// 197.769 us; speedup vs baseline: 1.0074x; 1.0074x over previous
//
#include <hip/hip_runtime.h>
#include <hip/hip_bf16.h>
#include <math.h>

// Problem constants (match reference)
#define BB 2
#define LL 4096
#define DD 128
#define ED 256
#define NN 16
#define KK 4
#define RR 8
#define HH 256
#define NT (BB*LL)          // 8192 tokens
#define NC 128              // chunks for scan
#define LC 32               // chunk length (NC*LC == LL)

typedef __attribute__((ext_vector_type(8))) short short8;
typedef __attribute__((ext_vector_type(8))) unsigned short ushort8v;
typedef __attribute__((ext_vector_type(4))) float floatx4;

__device__ __forceinline__ unsigned short f2bf(float f) {
  unsigned int b = __builtin_bit_cast(unsigned int, f);
  b += 0x7FFFu + ((b >> 16) & 1u);           // round-to-nearest-even
  return (unsigned short)(b >> 16);
}

__device__ __forceinline__ ushort8v pack8(const float4& v0, const float4& v1) {
  ushort8v p;
  p[0]=f2bf(v0.x); p[1]=f2bf(v0.y); p[2]=f2bf(v0.z); p[3]=f2bf(v0.w);
  p[4]=f2bf(v1.x); p[5]=f2bf(v1.y); p[6]=f2bf(v1.z); p[7]=f2bf(v1.w);
  return p;
}

// ---------------------------------------------------------------------------
// in_proj GEMM with fused double-LayerNorm on A and inline fp32->bf16 weight
// conversion. xz[M,512] = LN2(LN1(x)) @ in_w^T.  K = 128 = LN width.
// ---------------------------------------------------------------------------
__global__ __launch_bounds__(256) void gemm_inln_k(const float* __restrict__ x,
    const float* __restrict__ g1, const float* __restrict__ b1,
    const float* __restrict__ g2, const float* __restrict__ b2,
    const float* __restrict__ W, float* __restrict__ C) {
  __shared__ unsigned short As[64][136];
  __shared__ unsigned short Ws[64][136];
  const int row0 = blockIdx.y * 64;
  const int col0 = blockIdx.x * 64;
  const int tid  = threadIdx.x;
  const int wave = tid >> 6, lane = tid & 63;
  const int quad = lane >> 4, l16 = lane & 15;
  const int wm = (wave & 1) * 32, wn = (wave >> 1) * 32;
  const int lr = tid >> 2;            // staging row 0..63
  const int lk = (tid & 3) * 32;      // staging col (32 floats)

  // --- A staging with double LN ---
  {
    const float* Ap = x + (size_t)(row0 + lr)*DD + lk;
    float4 av[8];
    float s = 0.f, sq = 0.f;
    #pragma unroll
    for (int g = 0; g < 8; g++) {
      av[g] = *(const float4*)(Ap + g*4);
      s  += av[g].x + av[g].y + av[g].z + av[g].w;
      sq += av[g].x*av[g].x + av[g].y*av[g].y + av[g].z*av[g].z + av[g].w*av[g].w;
    }
    s += __shfl_xor(s, 1);  s += __shfl_xor(s, 2);
    sq += __shfl_xor(sq, 1); sq += __shfl_xor(sq, 2);
    const float m1 = s * (1.f/128.f);
    const float rs1 = rsqrtf(sq*(1.f/128.f) - m1*m1 + 1e-5f);
    float s2 = 0.f, sq2 = 0.f;
    #pragma unroll
    for (int g = 0; g < 8; g++) {
      const float4 gg = *(const float4*)(g1 + lk + g*4);
      const float4 bb = *(const float4*)(b1 + lk + g*4);
      av[g].x = (av[g].x - m1)*rs1*gg.x + bb.x;
      av[g].y = (av[g].y - m1)*rs1*gg.y + bb.y;
      av[g].z = (av[g].z - m1)*rs1*gg.z + bb.z;
      av[g].w = (av[g].w - m1)*rs1*gg.w + bb.w;
      s2  += av[g].x + av[g].y + av[g].z + av[g].w;
      sq2 += av[g].x*av[g].x + av[g].y*av[g].y + av[g].z*av[g].z + av[g].w*av[g].w;
    }
    s2 += __shfl_xor(s2, 1);  s2 += __shfl_xor(s2, 2);
    sq2 += __shfl_xor(sq2, 1); sq2 += __shfl_xor(sq2, 2);
    const float m2 = s2 * (1.f/128.f);
    const float rs2 = rsqrtf(sq2*(1.f/128.f) - m2*m2 + 1e-5f);
    #pragma unroll
    for (int g = 0; g < 4; g++) {
      const float4 ga = *(const float4*)(g2 + lk + g*8);
      const float4 gb = *(const float4*)(g2 + lk + g*8 + 4);
      const float4 ba = *(const float4*)(b2 + lk + g*8);
      const float4 bbv= *(const float4*)(b2 + lk + g*8 + 4);
      ushort8v pa;
      pa[0] = f2bf((av[2*g].x   - m2)*rs2*ga.x + ba.x);
      pa[1] = f2bf((av[2*g].y   - m2)*rs2*ga.y + ba.y);
      pa[2] = f2bf((av[2*g].z   - m2)*rs2*ga.z + ba.z);
      pa[3] = f2bf((av[2*g].w   - m2)*rs2*ga.w + ba.w);
      pa[4] = f2bf((av[2*g+1].x - m2)*rs2*gb.x + bbv.x);
      pa[5] = f2bf((av[2*g+1].y - m2)*rs2*gb.y + bbv.y);
      pa[6] = f2bf((av[2*g+1].z - m2)*rs2*gb.z + bbv.z);
      pa[7] = f2bf((av[2*g+1].w - m2)*rs2*gb.w + bbv.w);
      *(ushort8v*)&As[lr][lk + g*8] = pa;
    }
  }
  // --- W staging with inline conversion ---
  {
    const float* Wp = W + (size_t)(col0 + lr)*DD + lk;
    #pragma unroll
    for (int g = 0; g < 4; g++) {
      const float4 v0 = *(const float4*)(Wp + g*8);
      const float4 v1 = *(const float4*)(Wp + g*8 + 4);
      *(ushort8v*)&Ws[lr][lk + g*8] = pack8(v0, v1);
    }
  }
  __syncthreads();

  floatx4 acc[2][2] = {};
  #pragma unroll
  for (int ks = 0; ks < 4; ks++) {
    const int ko = ks*32 + quad*8;
    short8 a0 = *(const short8*)&As[wm +      l16][ko];
    short8 a1 = *(const short8*)&As[wm + 16 + l16][ko];
    short8 b0 = *(const short8*)&Ws[wn +      l16][ko];
    short8 b1 = *(const short8*)&Ws[wn + 16 + l16][ko];
    acc[0][0] = __builtin_amdgcn_mfma_f32_16x16x32_bf16(a0, b0, acc[0][0], 0, 0, 0);
    acc[0][1] = __builtin_amdgcn_mfma_f32_16x16x32_bf16(a0, b1, acc[0][1], 0, 0, 0);
    acc[1][0] = __builtin_amdgcn_mfma_f32_16x16x32_bf16(a1, b0, acc[1][0], 0, 0, 0);
    acc[1][1] = __builtin_amdgcn_mfma_f32_16x16x32_bf16(a1, b1, acc[1][1], 0, 0, 0);
  }
  #pragma unroll
  for (int i = 0; i < 2; i++)
    #pragma unroll
    for (int j = 0; j < 2; j++) {
      const int n = col0 + wn + j*16 + l16;
      #pragma unroll
      for (int r = 0; r < 4; r++) {
        const int m = row0 + wm + i*16 + quad*4 + r;
        C[(size_t)m*(2*ED) + n] = acc[i][j][r];
      }
    }
}

// ---------------------------------------------------------------------------
// Fused scan phase 1: conv+silu -> xproj(MFMA, inline W convert) -> delta ->
// per-chunk scan summaries. Grid (eb, c, b), 512 blocks, 2/CU.
// ---------------------------------------------------------------------------
__global__ __launch_bounds__(256) void scan1f_k(
    const float* __restrict__ xz, const float* __restrict__ cw,
    const float* __restrict__ cb, const float* __restrict__ xpw,
    const float* __restrict__ dtw, const float* __restrict__ dtb,
    const float* __restrict__ A_log, float* __restrict__ uc,
    float* __restrict__ dbc, float* __restrict__ delta,
    float* __restrict__ cA, float* __restrict__ cH) {
  __shared__ __align__(16) unsigned short Bs[64][264];
  __shared__ __align__(16) unsigned short As[32][264];
  __shared__ float su[32][128];
  __shared__ float sdbc[32][40];
  float (*sdel)[128] = reinterpret_cast<float(*)[128]>(&As[0][0]); // aliases As

  const int eb = blockIdx.x, c = blockIdx.y, b = blockIdx.z;
  const int tid = threadIdx.x;
  const int t0 = b*LL + c*LC;

  // stage xproj weights with inline conversion (rows >= 40 zeroed)
  #pragma unroll
  for (int p = 0; p < 8; p++) {
    const int idx = p*256 + tid;           // 2048 chunks of 8 shorts
    const int row = idx >> 5;
    const int col = (idx & 31) * 8;
    ushort8v v = {};
    if (row < 40) {
      const float4 v0 = *(const float4*)(xpw + (size_t)row*ED + col);
      const float4 v1 = *(const float4*)(xpw + (size_t)row*ED + col + 4);
      v = pack8(v0, v1);
    }
    *(ushort8v*)&Bs[row][col] = v;
  }

  // conv: rolling window, all 256 channels
  {
    const int ch = tid;
    const float4 w = *(const float4*)(cw + ch*4);
    const float cbe = cb[ch];
    float h0 = 0.f, h1 = 0.f, h2 = 0.f;
    if (c != 0) {
      h0 = xz[(size_t)(t0-3)*(2*ED) + ch];
      h1 = xz[(size_t)(t0-2)*(2*ED) + ch];
      h2 = xz[(size_t)(t0-1)*(2*ED) + ch];
    }
    const bool own = (ch >> 7) == eb;
    #pragma unroll 8
    for (int i = 0; i < LC; i++) {
      const float cur = xz[(size_t)(t0+i)*(2*ED) + ch];
      const float a = cbe + h0*w.x + h1*w.y + h2*w.z + cur*w.w;
      const float s = a / (1.f + __expf(-a));
      As[i][ch] = f2bf(s);
      if (own) {
        su[i][ch & 127] = s;
        uc[(size_t)(t0+i)*ED + ch] = s;
      }
      h0 = h1; h1 = h2; h2 = cur;
    }
  }
  __syncthreads();

  // xproj MFMA: M=32, N=64(pad), K=256
  const int wave = tid >> 6, lane = tid & 63;
  const int quad = lane >> 4, l16 = lane & 15;
  {
    const int mi = (wave & 1) * 16;
    const int j0 = (wave >> 1) * 2;
    floatx4 acc[2] = {};
    #pragma unroll
    for (int ks = 0; ks < 8; ks++) {
      const int ko = ks*32 + quad*8;
      short8 a  = *(const short8*)&As[mi + l16][ko];
      short8 b0 = *(const short8*)&Bs[j0*16 +      l16][ko];
      short8 b1 = *(const short8*)&Bs[j0*16 + 16 + l16][ko];
      acc[0] = __builtin_amdgcn_mfma_f32_16x16x32_bf16(a, b0, acc[0], 0, 0, 0);
      acc[1] = __builtin_amdgcn_mfma_f32_16x16x32_bf16(a, b1, acc[1], 0, 0, 0);
    }
    __syncthreads();   // As reads done before sdel aliases As
    #pragma unroll
    for (int f = 0; f < 2; f++) {
      const int n = (j0 + f)*16 + l16;
      #pragma unroll
      for (int r = 0; r < 4; r++) {
        const int m = mi + quad*4 + r;
        if (n < 40) {
          sdbc[m][n] = acc[f][r];
          if (eb == 0) dbc[(size_t)(t0 + m)*40 + n] = acc[f][r];
        }
      }
    }
  }
  __syncthreads();

  // delta: softplus(dt @ dt_w^T + dt_b) for own 128 channels
  const int e_loc = tid >> 1;
  const int half  = tid & 1;
  const int e     = eb*128 + e_loc;
  {
    const float4 w0 = *(const float4*)(dtw + e*RR);
    const float4 w1 = *(const float4*)(dtw + e*RR + 4);
    const float db = dtb[e];
    #pragma unroll 4
    for (int i = 0; i < 16; i++) {
      const int t = half*16 + i;
      const float a = db
          + sdbc[t][0]*w0.x + sdbc[t][1]*w0.y + sdbc[t][2]*w0.z + sdbc[t][3]*w0.w
          + sdbc[t][4]*w1.x + sdbc[t][5]*w1.y + sdbc[t][6]*w1.z + sdbc[t][7]*w1.w;
      const float d = (a > 20.f) ? a : log1pf(__expf(a));
      sdel[t][e_loc] = d;
      delta[(size_t)(t0+t)*ED + e] = d;
    }
  }
  __syncthreads();

  // per-chunk scan summaries; thread owns (e, n-half)
  const int n0 = half * 8;
  const float4 a0 = *(const float4*)(A_log + e*NN + n0);
  const float4 a1 = *(const float4*)(A_log + e*NN + n0 + 4);
  float Aen[8] = {-__expf(a0.x), -__expf(a0.y), -__expf(a0.z), -__expf(a0.w),
                  -__expf(a1.x), -__expf(a1.y), -__expf(a1.z), -__expf(a1.w)};
  float h[8] = {};
  float sumd = 0.f;
  for (int i = 0; i < LC; i++) {
    const float dv = sdel[i][e_loc];
    const float du = dv * su[i][e_loc];
    const float4 B0 = *(const float4*)&sdbc[i][RR + n0];
    const float4 B1 = *(const float4*)&sdbc[i][RR + n0 + 4];
    const float Bv[8] = {B0.x,B0.y,B0.z,B0.w,B1.x,B1.y,B1.z,B1.w};
    sumd += dv;
    #pragma unroll
    for (int j = 0; j < 8; j++)
      h[j] = __expf(dv * Aen[j])*h[j] + Bv[j]*du;
  }
  const size_t base = (((size_t)c*BB + b)*ED + e)*NN + n0;
  *(float4*)(cA + base)     = make_float4(__expf(sumd*Aen[0]), __expf(sumd*Aen[1]),
                                          __expf(sumd*Aen[2]), __expf(sumd*Aen[3]));
  *(float4*)(cA + base + 4) = make_float4(__expf(sumd*Aen[4]), __expf(sumd*Aen[5]),
                                          __expf(sumd*Aen[6]), __expf(sumd*Aen[7]));
  *(float4*)(cH + base)     = make_float4(h[0], h[1], h[2], h[3]);
  *(float4*)(cH + base + 4) = make_float4(h[4], h[5], h[6], h[7]);
}

// ---------------------------------------------------------------------------
// Scan phase 2: scan over NC chunk summaries, in-place prefix into cA.
// ---------------------------------------------------------------------------
__global__ __launch_bounds__(256) void scan2_k(float* __restrict__ cA,
    const float* __restrict__ cH) {
  const int gt = blockIdx.x*256 + threadIdx.x;   // [0, BB*ED*NN)
  const int b = gt >> 12;
  const size_t base = (size_t)b*ED*NN + (gt & 4095);
  float h = 0.f;
  for (int g = 0; g < NC/16; g++) {
    float av[16], hv[16];
    #pragma unroll
    for (int i = 0; i < 16; i++) {
      const size_t idx = (size_t)(g*16 + i)*(BB*ED*NN) + base;
      av[i] = cA[idx]; hv[i] = cH[idx];
    }
    #pragma unroll
    for (int i = 0; i < 16; i++) {
      const size_t idx = (size_t)(g*16 + i)*(BB*ED*NN) + base;
      cA[idx] = h;
      h = av[i]*h + hv[i];
    }
  }
}

// ---------------------------------------------------------------------------
// Mega-tail v3: 32-token chunks, 256 blocks, **512 threads = 8 waves/CU**
// (round 8 had 4). No warm-up duplication, weights staged once per block.
// Scan replay uses (e, n-half) split: h[8]/thread + 1 shuffle (round-5 form).
// MFMA phases use a 2m x 4n wave grid. LDS ~107.5 KB, 1 block/CU.
// ---------------------------------------------------------------------------
__global__ __launch_bounds__(512, 1) void tail3_k(
    const float* __restrict__ xz, const float* __restrict__ delta,
    const float* __restrict__ uc, const float* __restrict__ dbc,
    const float* __restrict__ cP, const float* __restrict__ A_log,
    const float* __restrict__ Dpv, const float* __restrict__ x,
    const float* __restrict__ g1, const float* __restrict__ b1,
    const float* __restrict__ out_w, const float* __restrict__ fc1_w,
    const float* __restrict__ fc1_b, const float* __restrict__ fc2_w,
    const float* __restrict__ fc2_b, float* __restrict__ out) {
  __shared__ __align__(16) unsigned short BigW[256*136];  // 69.6 KB
  __shared__ __align__(16) unsigned short Au[32][264];    // y -> hln -> h
  __shared__ float xs[32][132];                           // xnew tile fp32
  __shared__ float sbc[32][32];                           // B|C per token

  const int c = blockIdx.x, b = blockIdx.y;
  const int t0 = b*LL + c*LC;
  const int tid = threadIdx.x;        // 0..511
  const int wave = tid >> 6, lane = tid & 63;
  const int quad = lane >> 4, l16 = lane & 15;
  const int wm = (wave & 1) * 16;     // m-frag base for MFMA phases
  const int wq = wave >> 1;           // 0..3 n-group

  // --- stage B/C tile of dbc (1024 floats, 2/thread) ---
  #pragma unroll
  for (int p = 0; p < 2; p++) {
    const int idx = p*512 + tid;
    const int row = idx >> 5, col = idx & 31;
    sbc[row][col] = dbc[(size_t)(t0 + row)*40 + RR + col];
  }

  // --- scan replay: thread = (e, n-half), h[8] in regs + 1 shuffle ---
  {
    const int e = tid >> 1, half = tid & 1, n0 = half * 8;
    const float4 a0 = *(const float4*)(A_log + e*NN + n0);
    const float4 a1 = *(const float4*)(A_log + e*NN + n0 + 4);
    float Aen[8] = {-__expf(a0.x), -__expf(a0.y), -__expf(a0.z), -__expf(a0.w),
                    -__expf(a1.x), -__expf(a1.y), -__expf(a1.z), -__expf(a1.w)};
    const size_t pbase = (((size_t)c*BB + b)*ED + e)*NN + n0;
    const float4 h0 = *(const float4*)(cP + pbase);
    const float4 h1 = *(const float4*)(cP + pbase + 4);
    float h[8] = {h0.x,h0.y,h0.z,h0.w,h1.x,h1.y,h1.z,h1.w};
    const float Dpe = Dpv[e];
    __syncthreads();     // sbc ready
    #pragma unroll 4
    for (int i = 0; i < LC; i++) {
      const float dv = delta[(size_t)(t0+i)*ED + e];
      const float uv = uc[(size_t)(t0+i)*ED + e];
      const float du = dv * uv;
      float part = 0.f;
      #pragma unroll
      for (int j = 0; j < 8; j++) {
        h[j] = __expf(dv * Aen[j])*h[j] + sbc[i][n0 + j]*du;
        part += h[j]*sbc[i][16 + n0 + j];
      }
      part += __shfl_xor(part, 1);        // combine n-halves
      if (half == 0) {
        const float zv = xz[(size_t)(t0+i)*(2*ED) + ED + e];
        const float g = zv / (1.f + __expf(-zv));   // silu(z)
        Au[i][e] = f2bf((part + uv*Dpe) * g);
      }
    }
  }
  // --- stage out_w (128x256, stride 264): 4 thr/row, 64 k each ---
  {
    const int r = tid >> 2, k0 = (tid & 3) * 64;
    const float* wp = out_w + (size_t)r*ED + k0;
    #pragma unroll
    for (int g = 0; g < 8; g++) {
      const float4 v0 = *(const float4*)(wp + g*8);
      const float4 v1 = *(const float4*)(wp + g*8 + 4);
      *(ushort8v*)&BigW[r*264 + k0 + g*8] = pack8(v0, v1);
    }
  }
  __syncthreads();

  // --- out_proj MFMA: M=32, N=128, K=256; 8 waves = 2m x 4n(32) ---
  {
    const int wn = wq * 32;
    floatx4 acc[2] = {};
    #pragma unroll
    for (int ks = 0; ks < 8; ks++) {
      const int ko = ks*32 + quad*8;
      short8 a  = *(const short8*)&Au[wm + l16][ko];
      short8 b0 = *(const short8*)&BigW[(wn +      l16)*264 + ko];
      short8 b1 = *(const short8*)&BigW[(wn + 16 + l16)*264 + ko];
      acc[0] = __builtin_amdgcn_mfma_f32_16x16x32_bf16(a, b0, acc[0], 0, 0, 0);
      acc[1] = __builtin_amdgcn_mfma_f32_16x16x32_bf16(a, b1, acc[1], 0, 0, 0);
    }
    #pragma unroll
    for (int j = 0; j < 2; j++) {
      const int n = wn + j*16 + l16;
      #pragma unroll
      for (int r = 0; r < 4; r++) {
        const int m = wm + quad*4 + r;
        xs[m][n] = acc[j][r] + x[(size_t)(t0 + m)*DD + n];
      }
    }
  }
  __syncthreads();   // Au/BigW reads done; xs visible

  // --- norm1 per row (16 thr/row, 8 elems) -> hln into Au[.,0:128] ---
  {
    const int lr = tid >> 4, le = (tid & 15) * 8;
    float vv[8];
    float s = 0.f, sq = 0.f;
    #pragma unroll
    for (int i = 0; i < 8; i++) {
      vv[i] = xs[lr][le + i];
      s += vv[i]; sq += vv[i]*vv[i];
    }
    s += __shfl_xor(s, 1);  s += __shfl_xor(s, 2);
    s += __shfl_xor(s, 4);  s += __shfl_xor(s, 8);
    sq += __shfl_xor(sq, 1); sq += __shfl_xor(sq, 2);
    sq += __shfl_xor(sq, 4); sq += __shfl_xor(sq, 8);
    const float mean = s * (1.f/128.f);
    const float rs = rsqrtf(sq*(1.f/128.f) - mean*mean + 1e-5f);
    ushort8v p;
    #pragma unroll
    for (int i = 0; i < 8; i++)
      p[i] = f2bf((vv[i] - mean)*rs*g1[le + i] + b1[le + i]);
    *(ushort8v*)&Au[lr][le] = p;
  }
  // --- stage fc1_w (256x128, stride 136): 2 thr/row, 64 k each ---
  {
    const int r = tid >> 1, k0 = (tid & 1) * 64;
    const float* wp = fc1_w + (size_t)r*DD + k0;
    #pragma unroll
    for (int g = 0; g < 8; g++) {
      const float4 v0 = *(const float4*)(wp + g*8);
      const float4 v1 = *(const float4*)(wp + g*8 + 4);
      *(ushort8v*)&BigW[r*136 + k0 + g*8] = pack8(v0, v1);
    }
  }
  __syncthreads();   // hln + fc1 weights visible

  // --- fc1 MFMA: M=32, N=256, K=128; 8 waves = 2m x 4n(64); gelu -> Au ---
  {
    const int wn = wq * 64;
    floatx4 acc[4] = {};
    #pragma unroll
    for (int ks = 0; ks < 4; ks++) {
      const int ko = ks*32 + quad*8;
      short8 a = *(const short8*)&Au[wm + l16][ko];
      #pragma unroll
      for (int f = 0; f < 4; f++) {
        short8 bv = *(const short8*)&BigW[(wn + f*16 + l16)*136 + ko];
        acc[f] = __builtin_amdgcn_mfma_f32_16x16x32_bf16(a, bv, acc[f], 0, 0, 0);
      }
    }
    __syncthreads();   // all hln reads done before Au overwrite
    #pragma unroll
    for (int f = 0; f < 4; f++) {
      const int n = wn + f*16 + l16;
      const float bn = fc1_b[n];
      #pragma unroll
      for (int r = 0; r < 4; r++) {
        const int m = wm + quad*4 + r;
        float v = acc[f][r] + bn;
        v = 0.5f*v*(1.f + erff(v*0.70710678118f));
        Au[m][n] = f2bf(v);
      }
    }
  }
  __syncthreads();   // fc1 BigW reads done; Au(h) visible

  // --- stage fc2_w (128x256, stride 264): 4 thr/row, 64 k each ---
  {
    const int r = tid >> 2, k0 = (tid & 3) * 64;
    const float* wp = fc2_w + (size_t)r*HH + k0;
    #pragma unroll
    for (int g = 0; g < 8; g++) {
      const float4 v0 = *(const float4*)(wp + g*8);
      const float4 v1 = *(const float4*)(wp + g*8 + 4);
      *(ushort8v*)&BigW[r*264 + k0 + g*8] = pack8(v0, v1);
    }
  }
  __syncthreads();

  // --- fc2 MFMA: M=32, N=128, K=256; 8 waves = 2m x 4n(32); +bias +res ---
  {
    const int wn = wq * 32;
    floatx4 acc[2] = {};
    #pragma unroll
    for (int ks = 0; ks < 8; ks++) {
      const int ko = ks*32 + quad*8;
      short8 a  = *(const short8*)&Au[wm + l16][ko];
      short8 b0 = *(const short8*)&BigW[(wn +      l16)*264 + ko];
      short8 b1 = *(const short8*)&BigW[(wn + 16 + l16)*264 + ko];
      acc[0] = __builtin_amdgcn_mfma_f32_16x16x32_bf16(a, b0, acc[0], 0, 0, 0);
      acc[1] = __builtin_amdgcn_mfma_f32_16x16x32_bf16(a, b1, acc[1], 0, 0, 0);
    }
    #pragma unroll
    for (int j = 0; j < 2; j++) {
      const int n = wn + j*16 + l16;
      const float bn = fc2_b[n];
      #pragma unroll
      for (int r = 0; r < 4; r++) {
        const int m = wm + quad*4 + r;
        out[(size_t)(t0 + m)*DD + n] = acc[j][r] + bn + xs[m][n];
      }
    }
  }
}

// ---------------------------------------------------------------------------
extern "C" void kernel_launch(void* const* d_in, const int* in_sizes, int n_in,
                              void* d_out, int out_size, void* d_ws, size_t ws_size,
                              hipStream_t stream) {
  const float* x      = (const float*)d_in[0];
  const float* n1g    = (const float*)d_in[1];
  const float* n1b    = (const float*)d_in[2];
  const float* ing    = (const float*)d_in[3];
  const float* inb    = (const float*)d_in[4];
  const float* in_w   = (const float*)d_in[5];
  const float* conv_w = (const float*)d_in[6];
  const float* conv_b = (const float*)d_in[7];
  const float* xproj_w= (const float*)d_in[8];
  const float* dt_w   = (const float*)d_in[9];
  const float* dt_b   = (const float*)d_in[10];
  const float* A_log  = (const float*)d_in[11];
  const float* Dpv    = (const float*)d_in[12];
  const float* out_w  = (const float*)d_in[13];
  const float* fc1_w  = (const float*)d_in[14];
  const float* fc1_b  = (const float*)d_in[15];
  const float* fc2_w  = (const float*)d_in[16];
  const float* fc2_b  = (const float*)d_in[17];
  float* out = (float*)d_out;

  // Workspace layout (~37 MB)
  float* ws    = (float*)d_ws;
  float* xz    = ws;                          // [NT,512]
  float* uc    = xz    + (size_t)NT*2*ED;     // [NT,256]
  float* dbc   = uc    + (size_t)NT*ED;       // [NT,40]
  float* delta = dbc   + (size_t)NT*40;       // [NT,256]
  float* cAP   = delta + (size_t)NT*ED;       // [NC,B,ED,N]
  float* cH    = cAP   + (size_t)NC*BB*ED*NN;

  // 1) xz = LN2(LN1(x)) @ in_w^T   (LN + weight-convert fused)
  gemm_inln_k<<<dim3(512/64, NT/64), 256, 0, stream>>>(x, n1g, n1b, ing, inb, in_w, xz);
  // 2) conv+silu -> xproj(MFMA) -> delta -> chunk summaries
  scan1f_k<<<dim3(2, NC, BB), 256, 0, stream>>>(xz, conv_w, conv_b, xproj_w, dt_w, dt_b,
                                                A_log, uc, dbc, delta, cAP, cH);
  // 3) inter-chunk prefix
  scan2_k<<<(BB*ED*NN)/256, 256, 0, stream>>>(cAP, cH);
  // 4) scan replay + gate + out_proj + LN + MLP + residuals -> out (512 thr)
  tail3_k<<<dim3(NC, BB), 512, 0, stream>>>(xz, delta, uc, dbc, cAP, A_log, Dpv,
                                            x, n1g, n1b, out_w, fc1_w, fc1_b,
                                            fc2_w, fc2_b, out);
}

// Round 11
// 187.051 us; speedup vs baseline: 1.0651x; 1.0573x over previous
//
#include <hip/hip_runtime.h>
#include <hip/hip_bf16.h>
#include <math.h>

// Problem constants (match reference)
#define BB 2
#define LL 4096
#define DD 128
#define ED 256
#define NN 16
#define KK 4
#define RR 8
#define HH 256
#define NT (BB*LL)          // 8192 tokens
#define NC 128              // chunks for scan
#define LC 32               // chunk length (NC*LC == LL)

typedef __attribute__((ext_vector_type(8))) short short8;
typedef __attribute__((ext_vector_type(8))) unsigned short ushort8v;
typedef __attribute__((ext_vector_type(4))) float floatx4;

__device__ __forceinline__ unsigned short f2bf(float f) {
  unsigned int b = __builtin_bit_cast(unsigned int, f);
  b += 0x7FFFu + ((b >> 16) & 1u);           // round-to-nearest-even
  return (unsigned short)(b >> 16);
}

__device__ __forceinline__ ushort8v pack8(const float4& v0, const float4& v1) {
  ushort8v p;
  p[0]=f2bf(v0.x); p[1]=f2bf(v0.y); p[2]=f2bf(v0.z); p[3]=f2bf(v0.w);
  p[4]=f2bf(v1.x); p[5]=f2bf(v1.y); p[6]=f2bf(v1.z); p[7]=f2bf(v1.w);
  return p;
}

// ---------------------------------------------------------------------------
// in_proj GEMM with fused double-LayerNorm on A and inline fp32->bf16 weight
// conversion. xz[M,512] = LN2(LN1(x)) @ in_w^T.  K = 128 = LN width.
// ---------------------------------------------------------------------------
__global__ __launch_bounds__(256) void gemm_inln_k(const float* __restrict__ x,
    const float* __restrict__ g1, const float* __restrict__ b1,
    const float* __restrict__ g2, const float* __restrict__ b2,
    const float* __restrict__ W, float* __restrict__ C) {
  __shared__ unsigned short As[64][136];
  __shared__ unsigned short Ws[64][136];
  const int row0 = blockIdx.y * 64;
  const int col0 = blockIdx.x * 64;
  const int tid  = threadIdx.x;
  const int wave = tid >> 6, lane = tid & 63;
  const int quad = lane >> 4, l16 = lane & 15;
  const int wm = (wave & 1) * 32, wn = (wave >> 1) * 32;
  const int lr = tid >> 2;            // staging row 0..63
  const int lk = (tid & 3) * 32;      // staging col (32 floats)

  // --- A staging with double LN ---
  {
    const float* Ap = x + (size_t)(row0 + lr)*DD + lk;
    float4 av[8];
    float s = 0.f, sq = 0.f;
    #pragma unroll
    for (int g = 0; g < 8; g++) {
      av[g] = *(const float4*)(Ap + g*4);
      s  += av[g].x + av[g].y + av[g].z + av[g].w;
      sq += av[g].x*av[g].x + av[g].y*av[g].y + av[g].z*av[g].z + av[g].w*av[g].w;
    }
    s += __shfl_xor(s, 1);  s += __shfl_xor(s, 2);
    sq += __shfl_xor(sq, 1); sq += __shfl_xor(sq, 2);
    const float m1 = s * (1.f/128.f);
    const float rs1 = rsqrtf(sq*(1.f/128.f) - m1*m1 + 1e-5f);
    float s2 = 0.f, sq2 = 0.f;
    #pragma unroll
    for (int g = 0; g < 8; g++) {
      const float4 gg = *(const float4*)(g1 + lk + g*4);
      const float4 bb = *(const float4*)(b1 + lk + g*4);
      av[g].x = (av[g].x - m1)*rs1*gg.x + bb.x;
      av[g].y = (av[g].y - m1)*rs1*gg.y + bb.y;
      av[g].z = (av[g].z - m1)*rs1*gg.z + bb.z;
      av[g].w = (av[g].w - m1)*rs1*gg.w + bb.w;
      s2  += av[g].x + av[g].y + av[g].z + av[g].w;
      sq2 += av[g].x*av[g].x + av[g].y*av[g].y + av[g].z*av[g].z + av[g].w*av[g].w;
    }
    s2 += __shfl_xor(s2, 1);  s2 += __shfl_xor(s2, 2);
    sq2 += __shfl_xor(sq2, 1); sq2 += __shfl_xor(sq2, 2);
    const float m2 = s2 * (1.f/128.f);
    const float rs2 = rsqrtf(sq2*(1.f/128.f) - m2*m2 + 1e-5f);
    #pragma unroll
    for (int g = 0; g < 4; g++) {
      const float4 ga = *(const float4*)(g2 + lk + g*8);
      const float4 gb = *(const float4*)(g2 + lk + g*8 + 4);
      const float4 ba = *(const float4*)(b2 + lk + g*8);
      const float4 bbv= *(const float4*)(b2 + lk + g*8 + 4);
      ushort8v pa;
      pa[0] = f2bf((av[2*g].x   - m2)*rs2*ga.x + ba.x);
      pa[1] = f2bf((av[2*g].y   - m2)*rs2*ga.y + ba.y);
      pa[2] = f2bf((av[2*g].z   - m2)*rs2*ga.z + ba.z);
      pa[3] = f2bf((av[2*g].w   - m2)*rs2*ga.w + ba.w);
      pa[4] = f2bf((av[2*g+1].x - m2)*rs2*gb.x + bbv.x);
      pa[5] = f2bf((av[2*g+1].y - m2)*rs2*gb.y + bbv.y);
      pa[6] = f2bf((av[2*g+1].z - m2)*rs2*gb.z + bbv.z);
      pa[7] = f2bf((av[2*g+1].w - m2)*rs2*gb.w + bbv.w);
      *(ushort8v*)&As[lr][lk + g*8] = pa;
    }
  }
  // --- W staging with inline conversion ---
  {
    const float* Wp = W + (size_t)(col0 + lr)*DD + lk;
    #pragma unroll
    for (int g = 0; g < 4; g++) {
      const float4 v0 = *(const float4*)(Wp + g*8);
      const float4 v1 = *(const float4*)(Wp + g*8 + 4);
      *(ushort8v*)&Ws[lr][lk + g*8] = pack8(v0, v1);
    }
  }
  __syncthreads();

  floatx4 acc[2][2] = {};
  #pragma unroll
  for (int ks = 0; ks < 4; ks++) {
    const int ko = ks*32 + quad*8;
    short8 a0 = *(const short8*)&As[wm +      l16][ko];
    short8 a1 = *(const short8*)&As[wm + 16 + l16][ko];
    short8 b0 = *(const short8*)&Ws[wn +      l16][ko];
    short8 b1 = *(const short8*)&Ws[wn + 16 + l16][ko];
    acc[0][0] = __builtin_amdgcn_mfma_f32_16x16x32_bf16(a0, b0, acc[0][0], 0, 0, 0);
    acc[0][1] = __builtin_amdgcn_mfma_f32_16x16x32_bf16(a0, b1, acc[0][1], 0, 0, 0);
    acc[1][0] = __builtin_amdgcn_mfma_f32_16x16x32_bf16(a1, b0, acc[1][0], 0, 0, 0);
    acc[1][1] = __builtin_amdgcn_mfma_f32_16x16x32_bf16(a1, b1, acc[1][1], 0, 0, 0);
  }
  #pragma unroll
  for (int i = 0; i < 2; i++)
    #pragma unroll
    for (int j = 0; j < 2; j++) {
      const int n = col0 + wn + j*16 + l16;
      #pragma unroll
      for (int r = 0; r < 4; r++) {
        const int m = row0 + wm + i*16 + quad*4 + r;
        C[(size_t)m*(2*ED) + n] = acc[i][j][r];
      }
    }
}

// ---------------------------------------------------------------------------
// Fused scan phase 1: conv+silu -> xproj(MFMA, inline W convert) -> delta ->
// per-chunk scan summaries. Grid (eb, c, b), 512 blocks, 2/CU.
// Conv inputs fully preloaded (32 independent loads in flight).
// ---------------------------------------------------------------------------
__global__ __launch_bounds__(256) void scan1f_k(
    const float* __restrict__ xz, const float* __restrict__ cw,
    const float* __restrict__ cb, const float* __restrict__ xpw,
    const float* __restrict__ dtw, const float* __restrict__ dtb,
    const float* __restrict__ A_log, float* __restrict__ uc,
    float* __restrict__ dbc, float* __restrict__ delta,
    float* __restrict__ cA, float* __restrict__ cH) {
  __shared__ __align__(16) unsigned short Bs[64][264];
  __shared__ __align__(16) unsigned short As[32][264];
  __shared__ float su[32][128];
  __shared__ float sdbc[32][40];
  float (*sdel)[128] = reinterpret_cast<float(*)[128]>(&As[0][0]); // aliases As

  const int eb = blockIdx.x, c = blockIdx.y, b = blockIdx.z;
  const int tid = threadIdx.x;
  const int t0 = b*LL + c*LC;

  // stage xproj weights with inline conversion (rows >= 40 zeroed)
  #pragma unroll
  for (int p = 0; p < 8; p++) {
    const int idx = p*256 + tid;           // 2048 chunks of 8 shorts
    const int row = idx >> 5;
    const int col = (idx & 31) * 8;
    ushort8v v = {};
    if (row < 40) {
      const float4 v0 = *(const float4*)(xpw + (size_t)row*ED + col);
      const float4 v1 = *(const float4*)(xpw + (size_t)row*ED + col + 4);
      v = pack8(v0, v1);
    }
    *(ushort8v*)&Bs[row][col] = v;
  }

  // conv: all 32 inputs preloaded, rolling window in regs
  {
    const int ch = tid;
    const float4 w = *(const float4*)(cw + ch*4);
    const float cbe = cb[ch];
    float xv[32];
    #pragma unroll
    for (int i = 0; i < LC; i++)
      xv[i] = xz[(size_t)(t0+i)*(2*ED) + ch];
    float h0 = 0.f, h1 = 0.f, h2 = 0.f;
    if (c != 0) {
      h0 = xz[(size_t)(t0-3)*(2*ED) + ch];
      h1 = xz[(size_t)(t0-2)*(2*ED) + ch];
      h2 = xz[(size_t)(t0-1)*(2*ED) + ch];
    }
    const bool own = (ch >> 7) == eb;
    #pragma unroll
    for (int i = 0; i < LC; i++) {
      const float cur = xv[i];
      const float a = cbe + h0*w.x + h1*w.y + h2*w.z + cur*w.w;
      const float s = a / (1.f + __expf(-a));
      As[i][ch] = f2bf(s);
      if (own) {
        su[i][ch & 127] = s;
        uc[(size_t)(t0+i)*ED + ch] = s;
      }
      h0 = h1; h1 = h2; h2 = cur;
    }
  }
  __syncthreads();

  // xproj MFMA: M=32, N=64(pad), K=256
  const int wave = tid >> 6, lane = tid & 63;
  const int quad = lane >> 4, l16 = lane & 15;
  {
    const int mi = (wave & 1) * 16;
    const int j0 = (wave >> 1) * 2;
    floatx4 acc[2] = {};
    #pragma unroll
    for (int ks = 0; ks < 8; ks++) {
      const int ko = ks*32 + quad*8;
      short8 a  = *(const short8*)&As[mi + l16][ko];
      short8 b0 = *(const short8*)&Bs[j0*16 +      l16][ko];
      short8 b1 = *(const short8*)&Bs[j0*16 + 16 + l16][ko];
      acc[0] = __builtin_amdgcn_mfma_f32_16x16x32_bf16(a, b0, acc[0], 0, 0, 0);
      acc[1] = __builtin_amdgcn_mfma_f32_16x16x32_bf16(a, b1, acc[1], 0, 0, 0);
    }
    __syncthreads();   // As reads done before sdel aliases As
    #pragma unroll
    for (int f = 0; f < 2; f++) {
      const int n = (j0 + f)*16 + l16;
      #pragma unroll
      for (int r = 0; r < 4; r++) {
        const int m = mi + quad*4 + r;
        if (n < 40) {
          sdbc[m][n] = acc[f][r];
          if (eb == 0) dbc[(size_t)(t0 + m)*40 + n] = acc[f][r];
        }
      }
    }
  }
  __syncthreads();

  // delta: softplus(dt @ dt_w^T + dt_b) for own 128 channels
  const int e_loc = tid >> 1;
  const int half  = tid & 1;
  const int e     = eb*128 + e_loc;
  {
    const float4 w0 = *(const float4*)(dtw + e*RR);
    const float4 w1 = *(const float4*)(dtw + e*RR + 4);
    const float db = dtb[e];
    #pragma unroll 4
    for (int i = 0; i < 16; i++) {
      const int t = half*16 + i;
      const float a = db
          + sdbc[t][0]*w0.x + sdbc[t][1]*w0.y + sdbc[t][2]*w0.z + sdbc[t][3]*w0.w
          + sdbc[t][4]*w1.x + sdbc[t][5]*w1.y + sdbc[t][6]*w1.z + sdbc[t][7]*w1.w;
      const float d = (a > 20.f) ? a : log1pf(__expf(a));
      sdel[t][e_loc] = d;
      delta[(size_t)(t0+t)*ED + e] = d;
    }
  }
  __syncthreads();

  // per-chunk scan summaries; thread owns (e, n-half)
  const int n0 = half * 8;
  const float4 a0 = *(const float4*)(A_log + e*NN + n0);
  const float4 a1 = *(const float4*)(A_log + e*NN + n0 + 4);
  float Aen[8] = {-__expf(a0.x), -__expf(a0.y), -__expf(a0.z), -__expf(a0.w),
                  -__expf(a1.x), -__expf(a1.y), -__expf(a1.z), -__expf(a1.w)};
  float h[8] = {};
  float sumd = 0.f;
  for (int i = 0; i < LC; i++) {
    const float dv = sdel[i][e_loc];
    const float du = dv * su[i][e_loc];
    const float4 B0 = *(const float4*)&sdbc[i][RR + n0];
    const float4 B1 = *(const float4*)&sdbc[i][RR + n0 + 4];
    const float Bv[8] = {B0.x,B0.y,B0.z,B0.w,B1.x,B1.y,B1.z,B1.w};
    sumd += dv;
    #pragma unroll
    for (int j = 0; j < 8; j++)
      h[j] = __expf(dv * Aen[j])*h[j] + Bv[j]*du;
  }
  const size_t base = (((size_t)c*BB + b)*ED + e)*NN + n0;
  *(float4*)(cA + base)     = make_float4(__expf(sumd*Aen[0]), __expf(sumd*Aen[1]),
                                          __expf(sumd*Aen[2]), __expf(sumd*Aen[3]));
  *(float4*)(cA + base + 4) = make_float4(__expf(sumd*Aen[4]), __expf(sumd*Aen[5]),
                                          __expf(sumd*Aen[6]), __expf(sumd*Aen[7]));
  *(float4*)(cH + base)     = make_float4(h[0], h[1], h[2], h[3]);
  *(float4*)(cH + base + 4) = make_float4(h[4], h[5], h[6], h[7]);
}

// ---------------------------------------------------------------------------
// Scan phase 2: scan over NC chunk summaries, in-place prefix into cA.
// 64 blocks x 128 threads (2x the CU coverage of round 8).
// ---------------------------------------------------------------------------
__global__ __launch_bounds__(128) void scan2_k(float* __restrict__ cA,
    const float* __restrict__ cH) {
  const int gt = blockIdx.x*128 + threadIdx.x;   // [0, BB*ED*NN)
  const int b = gt >> 12;
  const size_t base = (size_t)b*ED*NN + (gt & 4095);
  float h = 0.f;
  for (int g = 0; g < NC/16; g++) {
    float av[16], hv[16];
    #pragma unroll
    for (int i = 0; i < 16; i++) {
      const size_t idx = (size_t)(g*16 + i)*(BB*ED*NN) + base;
      av[i] = cA[idx]; hv[i] = cH[idx];
    }
    #pragma unroll
    for (int i = 0; i < 16; i++) {
      const size_t idx = (size_t)(g*16 + i)*(BB*ED*NN) + base;
      cA[idx] = h;
      h = av[i]*h + hv[i];
    }
  }
}

// ---------------------------------------------------------------------------
// Mega-tail v4 (R8 structure + latency fixes): 32-token chunks, 256 blocks,
// 256 threads. (a) scan replay uses 8-deep batched register prefetch of
// delta/uc/z; (b) B/C read as wave-uniform scalar loads from dbc (no sbc LDS
// phase/barrier); (c) out_w staging moved before the replay.
// Arithmetic order identical to round 8 -> bit-identical output.
// ---------------------------------------------------------------------------
__global__ __launch_bounds__(256, 1) void tail4_k(
    const float* __restrict__ xz, const float* __restrict__ delta,
    const float* __restrict__ uc, const float* __restrict__ dbc,
    const float* __restrict__ cP, const float* __restrict__ A_log,
    const float* __restrict__ Dpv, const float* __restrict__ x,
    const float* __restrict__ g1, const float* __restrict__ b1,
    const float* __restrict__ out_w, const float* __restrict__ fc1_w,
    const float* __restrict__ fc1_b, const float* __restrict__ fc2_w,
    const float* __restrict__ fc2_b, float* __restrict__ out) {
  __shared__ __align__(16) unsigned short BigW[34816];  // 69.6 KB: Wo/W1/W2
  __shared__ __align__(16) unsigned short Au[32][264];  // y -> hln -> h (bf16)
  __shared__ float xs[32][132];                         // xnew tile fp32

  const int c = blockIdx.x, b = blockIdx.y;
  const int t0 = b*LL + c*LC;
  const int tid = threadIdx.x;
  const int wave = tid >> 6, lane = tid & 63;
  const int quad = lane >> 4, l16 = lane & 15;

  // --- stage out_w (128x256) -> BigW bf16, stride 264 (before replay) ---
  {
    const int r = tid >> 1, k0 = (tid & 1) * 128;
    const float* wp = out_w + (size_t)r*ED + k0;
    #pragma unroll
    for (int g = 0; g < 16; g++) {
      const float4 v0 = *(const float4*)(wp + g*8);
      const float4 v1 = *(const float4*)(wp + g*8 + 4);
      *(ushort8v*)&BigW[(size_t)r*264 + k0 + g*8] = pack8(v0, v1);
    }
  }

  // --- scan replay: thread = e, h[16] in regs, 8-deep batched prefetch ---
  {
    const int e = tid;
    float Aen[16], h[16];
    #pragma unroll
    for (int g = 0; g < 4; g++) {
      const float4 a = *(const float4*)(A_log + e*NN + g*4);
      Aen[4*g]=-__expf(a.x); Aen[4*g+1]=-__expf(a.y);
      Aen[4*g+2]=-__expf(a.z); Aen[4*g+3]=-__expf(a.w);
      const float4 hp = *(const float4*)(cP + (((size_t)c*BB + b)*ED + e)*NN + g*4);
      h[4*g]=hp.x; h[4*g+1]=hp.y; h[4*g+2]=hp.z; h[4*g+3]=hp.w;
    }
    const float Dpe = Dpv[e];
    float pd[8], pu[8], pz[8];
    #pragma unroll
    for (int i = 0; i < 8; i++) {
      pd[i] = delta[(size_t)(t0+i)*ED + e];
      pu[i] = uc[(size_t)(t0+i)*ED + e];
      pz[i] = xz[(size_t)(t0+i)*(2*ED) + ED + e];
    }
    for (int g4 = 0; g4 < 4; g4++) {
      float cd[8], cu[8], cz[8];
      #pragma unroll
      for (int i = 0; i < 8; i++) { cd[i]=pd[i]; cu[i]=pu[i]; cz[i]=pz[i]; }
      if (g4 < 3) {
        const int tn = t0 + (g4+1)*8;
        #pragma unroll
        for (int i = 0; i < 8; i++) {
          pd[i] = delta[(size_t)(tn+i)*ED + e];
          pu[i] = uc[(size_t)(tn+i)*ED + e];
          pz[i] = xz[(size_t)(tn+i)*(2*ED) + ED + e];
        }
      }
      #pragma unroll
      for (int i = 0; i < 8; i++) {
        const int t = g4*8 + i;
        const float dv = cd[i];
        const float uv = cu[i];
        const float du = dv * uv;
        // wave-uniform B/C loads (broadcast; scalar-cached)
        const float* bc = dbc + (size_t)(t0 + t)*40 + RR;
        const float4 B0 = *(const float4*)(bc);
        const float4 B1 = *(const float4*)(bc + 4);
        const float4 B2 = *(const float4*)(bc + 8);
        const float4 B3 = *(const float4*)(bc + 12);
        const float4 C0 = *(const float4*)(bc + 16);
        const float4 C1 = *(const float4*)(bc + 20);
        const float4 C2 = *(const float4*)(bc + 24);
        const float4 C3 = *(const float4*)(bc + 28);
        const float Bv[16] = {B0.x,B0.y,B0.z,B0.w, B1.x,B1.y,B1.z,B1.w,
                              B2.x,B2.y,B2.z,B2.w, B3.x,B3.y,B3.z,B3.w};
        const float Cv[16] = {C0.x,C0.y,C0.z,C0.w, C1.x,C1.y,C1.z,C1.w,
                              C2.x,C2.y,C2.z,C2.w, C3.x,C3.y,C3.z,C3.w};
        float part = 0.f;
        #pragma unroll
        for (int j = 0; j < 16; j++) {
          h[j] = __expf(dv * Aen[j])*h[j] + Bv[j]*du;
          part += h[j]*Cv[j];
        }
        const float g = cz[i] / (1.f + __expf(-cz[i]));   // silu(z)
        Au[t][e] = f2bf((part + uv*Dpe) * g);
      }
    }
  }
  __syncthreads();

  // --- out_proj MFMA: M=32, N=128, K=256; wave covers 32 n ---
  {
    const int wn = wave * 32;
    floatx4 acc[2][2] = {};
    #pragma unroll
    for (int ks = 0; ks < 8; ks++) {
      const int ko = ks*32 + quad*8;
      short8 a0 = *(const short8*)&Au[l16][ko];
      short8 a1 = *(const short8*)&Au[16 + l16][ko];
      short8 b0 = *(const short8*)&BigW[(size_t)(wn +      l16)*264 + ko];
      short8 b1 = *(const short8*)&BigW[(size_t)(wn + 16 + l16)*264 + ko];
      acc[0][0] = __builtin_amdgcn_mfma_f32_16x16x32_bf16(a0, b0, acc[0][0], 0, 0, 0);
      acc[0][1] = __builtin_amdgcn_mfma_f32_16x16x32_bf16(a0, b1, acc[0][1], 0, 0, 0);
      acc[1][0] = __builtin_amdgcn_mfma_f32_16x16x32_bf16(a1, b0, acc[1][0], 0, 0, 0);
      acc[1][1] = __builtin_amdgcn_mfma_f32_16x16x32_bf16(a1, b1, acc[1][1], 0, 0, 0);
    }
    #pragma unroll
    for (int i = 0; i < 2; i++)
      #pragma unroll
      for (int j = 0; j < 2; j++) {
        const int n = wn + j*16 + l16;
        #pragma unroll
        for (int r = 0; r < 4; r++) {
          const int m = i*16 + quad*4 + r;
          xs[m][n] = acc[i][j][r] + x[(size_t)(t0 + m)*DD + n];
        }
      }
  }
  __syncthreads();

  // --- norm1 per row (8 threads/row, 16 elems each) -> hln into Au[., 0:128]
  {
    const int lr = tid >> 3, le = (tid & 7) * 16;
    float vv[16];
    float s = 0.f, sq = 0.f;
    #pragma unroll
    for (int i = 0; i < 16; i++) {
      vv[i] = xs[lr][le + i];
      s += vv[i]; sq += vv[i]*vv[i];
    }
    s += __shfl_xor(s, 1);  s += __shfl_xor(s, 2);  s += __shfl_xor(s, 4);
    sq += __shfl_xor(sq, 1); sq += __shfl_xor(sq, 2); sq += __shfl_xor(sq, 4);
    const float mean = s * (1.f/128.f);
    const float rs = rsqrtf(sq*(1.f/128.f) - mean*mean + 1e-5f);
    #pragma unroll
    for (int g = 0; g < 2; g++) {
      ushort8v p;
      #pragma unroll
      for (int i = 0; i < 8; i++) {
        const int idx = g*8 + i;
        p[i] = f2bf((vv[idx] - mean)*rs*g1[le + idx] + b1[le + idx]);
      }
      *(ushort8v*)&Au[lr][le + g*8] = p;
    }
  }
  // --- stage fc1_w (256x128) -> BigW bf16, stride 136 ---
  {
    const float* wp = fc1_w + (size_t)tid*DD;
    #pragma unroll
    for (int g = 0; g < 16; g++) {
      const float4 v0 = *(const float4*)(wp + g*8);
      const float4 v1 = *(const float4*)(wp + g*8 + 4);
      *(ushort8v*)&BigW[(size_t)tid*136 + g*8] = pack8(v0, v1);
    }
  }
  __syncthreads();

  // --- fc1 MFMA: M=32, N=256, K=128; wave covers 64 n; gelu -> h into Au ---
  {
    const int wn = wave * 64;
    floatx4 acc[2][4] = {};
    #pragma unroll
    for (int ks = 0; ks < 4; ks++) {
      const int ko = ks*32 + quad*8;
      short8 a0 = *(const short8*)&Au[l16][ko];
      short8 a1 = *(const short8*)&Au[16 + l16][ko];
      #pragma unroll
      for (int f = 0; f < 4; f++) {
        short8 bv = *(const short8*)&BigW[(size_t)(wn + f*16 + l16)*136 + ko];
        acc[0][f] = __builtin_amdgcn_mfma_f32_16x16x32_bf16(a0, bv, acc[0][f], 0, 0, 0);
        acc[1][f] = __builtin_amdgcn_mfma_f32_16x16x32_bf16(a1, bv, acc[1][f], 0, 0, 0);
      }
    }
    __syncthreads();   // all hln reads done before Au is overwritten with h
    #pragma unroll
    for (int i = 0; i < 2; i++)
      #pragma unroll
      for (int f = 0; f < 4; f++) {
        const int n = wn + f*16 + l16;
        const float bn = fc1_b[n];
        #pragma unroll
        for (int r = 0; r < 4; r++) {
          const int m = i*16 + quad*4 + r;
          float v = acc[i][f][r] + bn;
          v = 0.5f*v*(1.f + erff(v*0.70710678118f));
          Au[m][n] = f2bf(v);
        }
      }
  }
  // --- stage fc2_w (128x256) -> BigW bf16, stride 264 ---
  {
    const int r = tid >> 1, k0 = (tid & 1) * 128;
    const float* wp = fc2_w + (size_t)r*HH + k0;
    __syncthreads();   // fc1 acc written to Au AND old BigW reads done
    #pragma unroll
    for (int g = 0; g < 16; g++) {
      const float4 v0 = *(const float4*)(wp + g*8);
      const float4 v1 = *(const float4*)(wp + g*8 + 4);
      *(ushort8v*)&BigW[(size_t)r*264 + k0 + g*8] = pack8(v0, v1);
    }
  }
  __syncthreads();

  // --- fc2 MFMA: M=32, N=128, K=256; + bias + xnew residual -> out ---
  {
    const int wn = wave * 32;
    floatx4 acc[2][2] = {};
    #pragma unroll
    for (int ks = 0; ks < 8; ks++) {
      const int ko = ks*32 + quad*8;
      short8 a0 = *(const short8*)&Au[l16][ko];
      short8 a1 = *(const short8*)&Au[16 + l16][ko];
      short8 b0 = *(const short8*)&BigW[(size_t)(wn +      l16)*264 + ko];
      short8 b1 = *(const short8*)&BigW[(size_t)(wn + 16 + l16)*264 + ko];
      acc[0][0] = __builtin_amdgcn_mfma_f32_16x16x32_bf16(a0, b0, acc[0][0], 0, 0, 0);
      acc[0][1] = __builtin_amdgcn_mfma_f32_16x16x32_bf16(a0, b1, acc[0][1], 0, 0, 0);
      acc[1][0] = __builtin_amdgcn_mfma_f32_16x16x32_bf16(a1, b0, acc[1][0], 0, 0, 0);
      acc[1][1] = __builtin_amdgcn_mfma_f32_16x16x32_bf16(a1, b1, acc[1][1], 0, 0, 0);
    }
    #pragma unroll
    for (int i = 0; i < 2; i++)
      #pragma unroll
      for (int j = 0; j < 2; j++) {
        const int n = wn + j*16 + l16;
        const float bn = fc2_b[n];
        #pragma unroll
        for (int r = 0; r < 4; r++) {
          const int m = i*16 + quad*4 + r;
          out[(size_t)(t0 + m)*DD + n] = acc[i][j][r] + bn + xs[m][n];
        }
      }
  }
}

// ---------------------------------------------------------------------------
extern "C" void kernel_launch(void* const* d_in, const int* in_sizes, int n_in,
                              void* d_out, int out_size, void* d_ws, size_t ws_size,
                              hipStream_t stream) {
  const float* x      = (const float*)d_in[0];
  const float* n1g    = (const float*)d_in[1];
  const float* n1b    = (const float*)d_in[2];
  const float* ing    = (const float*)d_in[3];
  const float* inb    = (const float*)d_in[4];
  const float* in_w   = (const float*)d_in[5];
  const float* conv_w = (const float*)d_in[6];
  const float* conv_b = (const float*)d_in[7];
  const float* xproj_w= (const float*)d_in[8];
  const float* dt_w   = (const float*)d_in[9];
  const float* dt_b   = (const float*)d_in[10];
  const float* A_log  = (const float*)d_in[11];
  const float* Dpv    = (const float*)d_in[12];
  const float* out_w  = (const float*)d_in[13];
  const float* fc1_w  = (const float*)d_in[14];
  const float* fc1_b  = (const float*)d_in[15];
  const float* fc2_w  = (const float*)d_in[16];
  const float* fc2_b  = (const float*)d_in[17];
  float* out = (float*)d_out;

  // Workspace layout (~37 MB)
  float* ws    = (float*)d_ws;
  float* xz    = ws;                          // [NT,512]
  float* uc    = xz    + (size_t)NT*2*ED;     // [NT,256]
  float* dbc   = uc    + (size_t)NT*ED;       // [NT,40]
  float* delta = dbc   + (size_t)NT*40;       // [NT,256]
  float* cAP   = delta + (size_t)NT*ED;       // [NC,B,ED,N]
  float* cH    = cAP   + (size_t)NC*BB*ED*NN;

  // 1) xz = LN2(LN1(x)) @ in_w^T   (LN + weight-convert fused)
  gemm_inln_k<<<dim3(512/64, NT/64), 256, 0, stream>>>(x, n1g, n1b, ing, inb, in_w, xz);
  // 2) conv+silu -> xproj(MFMA) -> delta -> chunk summaries
  scan1f_k<<<dim3(2, NC, BB), 256, 0, stream>>>(xz, conv_w, conv_b, xproj_w, dt_w, dt_b,
                                                A_log, uc, dbc, delta, cAP, cH);
  // 3) inter-chunk prefix
  scan2_k<<<(BB*ED*NN)/128, 128, 0, stream>>>(cAP, cH);
  // 4) scan replay + gate + out_proj + LN + MLP + residuals -> out
  tail4_k<<<dim3(NC, BB), 256, 0, stream>>>(xz, delta, uc, dbc, cAP, A_log, Dpv,
                                            x, n1g, n1b, out_w, fc1_w, fc1_b,
                                            fc2_w, fc2_b, out);
}